// Round 12
// baseline (674.048 us; speedup 1.0000x reference)
//
#include <hip/hip_runtime.h>

static constexpr int B_    = 64;
static constexpr int NIN   = 784;
static constexpr int NH    = 2048;
static constexpr int NOUT  = 10;
static constexpr int NN    = 2058;
static constexpr int NE    = 262144;
static constexpr int CAP   = 208;       // max in/out-degree bound (proven r3)
static constexpr int TPB   = 1024;
static constexpr int NTAB  = NH * 10;   // rail table: key = (d-6)*2048 + src

// ---- workspace layout (float-element offsets) ----
static constexpr size_t TABG_OFF  = 0;                               // 2 bufs * 64 * NTAB
static constexpr size_t IC_OFF    = TABG_OFF + 2ull * B_ * NTAB;     // B_*NH
static constexpr size_t ERECT_OFF = IC_OFF + (size_t)B_ * NH;        // 2*CAP*NN words
static constexpr size_t CUR_OFF   = ERECT_OFF + 2ull * CAP * NN;     // NN (+pad)
static constexpr size_t BARS_OFF  = CUR_OFF + 2060;                  // 64

// ------- prep: fused input-GEMM (all 512 blocks) + edge scatter (blocks 0-15) -------
__global__ __launch_bounds__(256) void prep_kernel(
    const float* __restrict__ x, const float* __restrict__ inW,
    const int* __restrict__ src, const int* __restrict__ tgt,
    const float* __restrict__ We, const float* __restrict__ Le,
    float* __restrict__ IC, int* __restrict__ cur, int2* __restrict__ erecT)
{
    const int tid = threadIdx.x;
    // ---- IC[b][n] = sum_k x[b,k] * inW[k,n] ----
    {
        const int id = blockIdx.x * 256 + tid;       // covers B_*NH exactly
        const int b = id >> 11, n = id & (NH - 1);
        float c = 0.f;
        #pragma unroll 8
        for (int k = 0; k < NIN; ++k)
            c = fmaf(x[b * NIN + k], inW[(size_t)k * NH + n], c);
        IC[b * NH + n] = c;
    }
    // ---- scatter edges into transposed padded CSR: erecT[i*NN + tgt] ----
    if (blockIdx.x < 16) {
        __shared__ int lh[NN];
        __shared__ int lbase[NN];
        for (int i = tid; i < NN; i += 256) lh[i] = 0;
        __syncthreads();
        const int base = blockIdx.x * (NE / 16);
        for (int k = 0; k < NE / 16; k += 256)
            atomicAdd(&lh[tgt[base + k + tid]], 1);
        __syncthreads();
        for (int i = tid; i < NN; i += 256) {
            int c = lh[i];
            lbase[i] = c ? atomicAdd(&cur[i], c) : 0;
            lh[i] = 0;
        }
        __syncthreads();
        for (int k = 0; k < NE / 16; k += 256) {
            const int e  = base + k + tid;
            const int tg = tgt[e];
            const int p  = lbase[tg] + atomicAdd(&lh[tg], 1);
            const int d  = (int)(Le[e] * 2.0f + 0.5f);   // 2L in {6..15}, exact on 0.5 grid
            if (p < CAP)                                 // proven: never exceeded
                erecT[(size_t)p * NN + tg] =
                    make_int2((d - 6) * NH + src[e], __float_as_int(We[e]));
        }
    }
}

// ---------------- SNN sim: block = (quarter q, batch b), rail table in LDS ----------------
__global__ __launch_bounds__(TPB, 4) void sim_kernel(
    const int2* __restrict__ erecT, const float* __restrict__ IC,
    float* __restrict__ tabG, int* __restrict__ bars, float* __restrict__ out)
{
    const int t = threadIdx.x;
    const int q = blockIdx.x >> 6;               // neuron quarter 0..3
    const int b = blockIdx.x & 63;               // batch (siblings 64 apart -> same XCD)
    const int hn = t & 511;                      // local neuron 0..511
    const int h  = t >> 9;                       // gather half 0/1
    const int n  = (q << 9) + hn;                // global hidden neuron id

    __shared__ float4 tab4[NTAB / 4];            // full rail snapshot, 80 KB
    float* __restrict__ tab = (float*)tab4;
    __shared__ float part[512][6];               // half-1 partial Ia (12 KB)
    __shared__ float opart[80][6];               // output-helper partials (1.9 KB)

    const bool owner = (t < 512);
    const bool oOwn  = (q == 3) && (t < NOUT);   // output-neuron owner
    const bool oHelp = (q == 3) && (t >= 944);   // 8 helpers x 10 outputs
    const int  ho = t - 944, oo = ho >> 3, os = ho & 7;

    const float ic = owner ? IC[b * NH + n] : 0.f;

    // per-(src,d) rail state, d = j+6 (r7-r11 verified): pa = pending-arrival, pv = value
    int pa[10]; float pv[10];
    #pragma unroll
    for (int j = 0; j < 10; ++j) { pa[j] = -1; pv[j] = 0.f; }
    float Vm = 0.f, Vo = 0.f, acc = 0.f;

    for (int k = 0; k < 5; ++k) {                // 5 windows of 6 steps
        const int t0 = 6 * k;
        float Ia[6] = {}, Io[6] = {};

        if (k) {
            // ---- bulk copy: global snapshot (written at k-1, barrier-ordered) -> LDS ----
            const float4* __restrict__ g4 =
                (const float4*)(tabG + ((size_t)((k & 1) * B_ + b)) * NTAB);
            #pragma unroll
            for (int i = 0; i < 5; ++i) tab4[i * TPB + t] = g4[i * TPB + t];
            __syncthreads();

            // ---- gather own half-neuron: 104 edges, 8-deep batches (verified decode) ----
            const int ib = h * 104;
            for (int i0 = ib; i0 < ib + 104; i0 += 8) {
                int kx[8]; float w8[8], tv[8];
                #pragma unroll
                for (int u = 0; u < 8; ++u) {            // coalesced 8B loads
                    const int2 e = erecT[(size_t)(i0 + u) * NN + n];
                    kx[u] = e.x; w8[u] = __int_as_float(e.y);
                }
                #pragma unroll
                for (int u = 0; u < 8; ++u) tv[u] = tab[kx[u]];
                #pragma unroll
                for (int u = 0; u < 8; ++u) {            // pad entries: w=0 -> adds 0
                    const unsigned uw = __float_as_uint(tv[u]);
                    const int tau = uw & 7;              // arrival offset, 7 = none
                    const float vw = __uint_as_float(uw & ~7u) * w8[u];
                    #pragma unroll
                    for (int jt = 0; jt < 6; ++jt)
                        Ia[jt] += (tau == jt) ? vw : 0.f;
                }
            }
            // ---- output helpers: 26 edges each of output oo ----
            if (oHelp) {
                float Ih[6] = {};
                for (int i0 = os * 26; i0 < os * 26 + 26; ++i0) {
                    const int2 e = erecT[(size_t)i0 * NN + (NH + oo)];
                    const unsigned uw = __float_as_uint(tab[e.x]);
                    const int tau = uw & 7;
                    const float vw = __uint_as_float(uw & ~7u) * __int_as_float(e.y);
                    #pragma unroll
                    for (int jt = 0; jt < 6; ++jt)
                        Ih[jt] += (tau == jt) ? vw : 0.f;
                }
                #pragma unroll
                for (int j = 0; j < 6; ++j) opart[ho][j] = Ih[j];
            }
            if (h == 1) {
                #pragma unroll
                for (int j = 0; j < 6; ++j) part[hn][j] = Ia[j];
            }
            __syncthreads();
            if (owner) {
                #pragma unroll
                for (int j = 0; j < 6; ++j) Ia[j] += part[t][j];
            }
            if (oOwn) {
                #pragma unroll
                for (int s = 0; s < 8; ++s)
                    #pragma unroll
                    for (int j = 0; j < 6; ++j) Io[j] += opart[t * 8 + s][j];
            }
        }

        // ---- neuron phase: 6 steps, registers only (verified math) ----
        if (owner) {
            #pragma unroll
            for (int j = 0; j < 6; ++j) {
                const int tt = t0 + j;
                const float I = Ia[j] + ((j == 2 || j == 5) ? ic : 0.f); // t%3==2 injection
                Vm += (I - Vm) * 0.1f;                                   // DT/TAU
                const float vex = fmaxf(Vm - 0.25f, 0.f);
                const bool f = vex > 0.f;
                #pragma unroll
                for (int jd = 0; jd < 10; ++jd)                          // launch on idle rails
                    if (f & (tt > pa[jd])) { pa[jd] = tt + jd + 6; pv[jd] = vex; }
                if (f) Vm = -0.2f;                                       // reset + AHP
            }
        }
        if (oOwn) {
            #pragma unroll
            for (int j = 0; j < 6; ++j) { Vo += (Io[j] - Vo) * 0.1f; acc += Vo; }
        }

        // ---- publish quarter snapshot (coalesced) + 4-block batch barrier ----
        if (k < 4) {
            if (owner) {
                float* __restrict__ og =
                    tabG + ((size_t)(((k + 1) & 1) * B_ + b)) * NTAB;
                const int t0n = t0 + 6;
                #pragma unroll
                for (int j = 0; j < 10; ++j) {           // tau-in-mantissa pack (proven)
                    const unsigned u = (unsigned)(pa[j] - t0n);
                    const unsigned code = (u < 6u) ? u : 7u;
                    og[j * NH + n] =
                        __uint_as_float((__float_as_uint(pv[j]) & ~7u) | code);
                }
            }
            __threadfence();                             // publishes visible (agent)
            __syncthreads();
            if (t == 0) {                                // r9-proven spin barrier
                __hip_atomic_fetch_add(&bars[b], 1, __ATOMIC_RELEASE,
                                       __HIP_MEMORY_SCOPE_AGENT);
                while (__hip_atomic_load(&bars[b], __ATOMIC_ACQUIRE,
                                         __HIP_MEMORY_SCOPE_AGENT) < 4 * (k + 1))
                    __builtin_amdgcn_s_sleep(1);
            }
            __syncthreads();
        }
    }

    if (oOwn) out[b * NOUT + t] = acc * (1.0f / 30.0f);
}

extern "C" void kernel_launch(void* const* d_in, const int* in_sizes, int n_in,
                              void* d_out, int out_size, void* d_ws, size_t ws_size,
                              hipStream_t stream) {
    const float* x   = (const float*)d_in[0];
    const float* inW = (const float*)d_in[1];
    const float* We  = (const float*)d_in[2];
    const float* Le  = (const float*)d_in[3];
    const int*   src = (const int*)d_in[4];
    const int*   tgt = (const int*)d_in[5];

    float* ws    = (float*)d_ws;
    float* tabG  = ws + TABG_OFF;
    float* IC    = ws + IC_OFF;
    int2*  erecT = (int2*)(ws + ERECT_OFF);
    int*   cur   = (int*)(ws + CUR_OFF);
    int*   bars  = (int*)(ws + BARS_OFF);
    float* out   = (float*)d_out;

    // one contiguous memset: erecT pad (w=0) + cursors + barrier counters
    hipMemsetAsync(erecT, 0, (2ull * CAP * NN + 2060 + 64) * sizeof(float), stream);

    prep_kernel<<<dim3(512), dim3(256), 0, stream>>>(x, inW, src, tgt, We, Le,
                                                     IC, cur, erecT);
    sim_kernel<<<dim3(256), dim3(TPB), 0, stream>>>(erecT, IC, tabG, bars, out);
}